// Round 9
// baseline (168.884 us; speedup 1.0000x reference)
//
#include <hip/hip_runtime.h>
#include <stdint.h>
#include <math.h>

#define NQ    2562
#define MPTS  16384
#define QPB   4            // queries per block
#define NBQ   641          // ceil(NQ / QPB) blocks per point cloud
#define CHUNK 4096         // points per wave (M split across 4 waves)
#define NT    (CHUNK / 256)// 16 stream iters per wave
#define CAP   320          // stack cap per (wave,query): 63 leftover + 256 worst-case iter

// ---------------------------------------------------------------------------
// Kernel 1: copy inputs [N,3] into output columns 0..2 of [N,15]
// ---------------------------------------------------------------------------
__global__ __launch_bounds__(256)
void passthrough_kernel(const float* __restrict__ inp, float* __restrict__ out) {
    int gid = blockIdx.x * 256 + threadIdx.x;
    if (gid < NQ * 3) {
        int n = gid / 3, c = gid - n * 3;
        out[n * 15 + c] = inp[gid];
    }
}

// key = (x^2sum + y^2sum) - 2*x.y  mirroring numpy association (left-assoc _rn,
// fma dot with pre-doubled query coords). Same formula in stream and rebuild
// -> bitwise-identical keys.
__device__ __forceinline__ float sqsum3(float y0, float y1, float y2) {
    return __fadd_rn(__fadd_rn(__fmul_rn(y0, y0), __fmul_rn(y1, y1)),
                     __fmul_rn(y2, y2));
}
__device__ __forceinline__ float keyf(float xs, float a2, float b2, float c2,
                                      float y0, float y1, float y2, float ysq) {
    float u = fmaf(c2, y2, fmaf(b2, y1, __fmul_rn(a2, y0)));
    return __fsub_rn(__fadd_rn(xs, ysq), u);
}
__device__ __forceinline__ unsigned long long packkey(float k, int m) {
    uint32_t kb = __float_as_uint(k);
    kb ^= (uint32_t)((int32_t)kb >> 31) | 0x80000000u;  // monotonic total-order map
    return ((unsigned long long)kb << 32) | (unsigned)m;
}
__device__ __forceinline__ float unmapkey(unsigned long long pk) {
    uint32_t kb = (uint32_t)(pk >> 32);
    return __uint_as_float((kb & 0x80000000u) ? (kb ^ 0x80000000u) : ~kb);
}
// popcount of mask over lanes < this lane (v_mbcnt pair)
__device__ __forceinline__ int prefix_lt(unsigned long long m) {
    return __builtin_amdgcn_mbcnt_hi((unsigned)(m >> 32),
           __builtin_amdgcn_mbcnt_lo((unsigned)m, 0u));
}

// 64-lane bitonic sort ascending; lane l ends with the l-th smallest value.
__device__ __forceinline__ unsigned long long sort64(unsigned long long v, int lane) {
#pragma unroll
    for (int k = 2; k <= 64; k <<= 1) {
#pragma unroll
        for (int j = k >> 1; j > 0; j >>= 1) {
            unsigned long long p = __shfl_xor(v, j);
            bool up = ((lane & k) == 0) == ((lane & j) == 0);
            bool sw = up ? (p < v) : (v < p);
            v = sw ? p : v;
        }
    }
    return v;
}

// Wave-collective: fold stack chunks into sorted t16 (LDS). Mid-stream
// (fin=false): process only full 64-chunks, compact remainder. Final
// (fin=true): process all. cnt is wave-uniform (register). Returns new tau.
__device__ __forceinline__ float rebuild_q(unsigned long long* t16p,
                                           unsigned* S, int& cnt, int lane,
                                           const float* __restrict__ P,
                                           float xs, float a2, float b2, float c2,
                                           bool fin) {
    int c = cnt;
    int full = c >> 6, rem = c & 63;
    int rounds = full + ((fin && rem) ? 1 : 0);
    unsigned long long v = ~0ULL;
    for (int rd = 0; rd < rounds; ++rd) {
        int i = (rd << 6) + lane;
        unsigned idx = (i < c) ? S[i] : 0u;
        float y0 = P[idx], y1 = P[MPTS + idx], y2 = P[2 * MPTS + idx];
        float key = keyf(xs, a2, b2, c2, y0, y1, y2, sqsum3(y0, y1, y2));
        unsigned long long pk = (i < c) ? packkey(key, (int)idx) : ~0ULL;
        pk = sort64(pk, lane);             // asc across lanes
        // bitonic merge: A = t16 asc (lanes 0-15), B = chunk's smallest-16 desc
        unsigned long long bsw = __shfl(pk, (31 - lane) & 63);
        v = (lane < 16) ? t16p[lane & 15] : (lane < 32) ? bsw : ~0ULL;
#pragma unroll
        for (int j = 16; j > 0; j >>= 1) {
            unsigned long long p2 = __shfl_xor(v, j);
            bool keepmin = (lane & j) == 0;
            bool less = p2 < v;
            v = (keepmin == less) ? p2 : v;
        }
        if (lane < 16) t16p[lane] = v;
    }
    if (!fin) {
        if (lane < rem) S[lane] = S[(full << 6) + lane];   // disjoint (full>=1)
        cnt = rem;
    } else {
        cnt = 0;
    }
    return unmapkey(__shfl(v, 15));
}

// ---------------------------------------------------------------------------
// Kernel 2: grid 4*NBQ x 256. Block b: pc = b/NBQ, queries 4*(b%NBQ)+r.
// All 4 waves share the same 4 queries; wave wid streams points
// [wid*4096, (wid+1)*4096). Selection: f32 tau gate + LDS index stack
// (offsets via ballot prefix-sum, counter in SGPR) + batched exact folds
// (sort64 + bitonic merge) into sorted t16. Tail: per-query 64-way sort
// merges the 4 chunk-top16s.
// ---------------------------------------------------------------------------
__global__ __launch_bounds__(256)
void knn_kernel(const float* __restrict__ inp,
                const float* __restrict__ pc0, const float* __restrict__ pc1,
                const float* __restrict__ pc2, const float* __restrict__ pc3,
                float* __restrict__ out) {
    const int b    = blockIdx.x;
    const int wid  = threadIdx.x >> 6;
    const int lane = threadIdx.x & 63;

    const int pc = b / NBQ;
    const int nb = b - pc * NBQ;
    const float* __restrict__ P = (pc == 0) ? pc0 : (pc == 1) ? pc1
                                : (pc == 2) ? pc2 : pc3;

    __shared__ unsigned           stk_sh[4][4][CAP];
    __shared__ unsigned long long t16_sh[4][4][16];

    t16_sh[wid][lane >> 4][lane & 15] = ~0ULL;

    // coefficients for the block's 4 queries
    float A2[4], B2[4], C2[4], XS[4];
#pragma unroll
    for (int r = 0; r < 4; ++r) {
        int n = QPB * nb + r;
        n = (n < NQ) ? n : (NQ - 1);       // tail clamp (duplicate-identical work)
        float x0 = inp[n * 3 + 0];
        float x1 = inp[n * 3 + 1];
        float x2 = inp[n * 3 + 2];
        A2[r] = 2.0f * x0;
        B2[r] = 2.0f * x1;
        C2[r] = 2.0f * x2;
        XS[r] = sqsum3(x0, x1, x2);
    }
    float tau[4];
    int   cnt[4] = {0, 0, 0, 0};           // wave-uniform -> SGPR

    const float* __restrict__ Pl = P + wid * CHUNK + (lane << 2);

    // prefetch t=0
    float4 cx = *(const float4*)(Pl);
    float4 cy = *(const float4*)(Pl + MPTS);
    float4 cz = *(const float4*)(Pl + 2 * MPTS);

    for (int t = 0; t < NT; ++t) {
        // prefetch t+1 (wraps to t=0 on last iter; harmless L2 re-hit)
        const int tn = (t + 1) & (NT - 1);
        float4 nx = *(const float4*)(Pl + (tn << 8));
        float4 ny = *(const float4*)(Pl + MPTS + (tn << 8));
        float4 nz = *(const float4*)(Pl + 2 * MPTS + (tn << 8));

        const int mofs = wid * CHUNK + (t << 8) + (lane << 2);
        float q0 = sqsum3(cx.x, cy.x, cz.x);
        float q1 = sqsum3(cx.y, cy.y, cz.y);
        float q2 = sqsum3(cx.z, cy.z, cz.z);
        float q3 = sqsum3(cx.w, cy.w, cz.w);

        float k0[4], k1[4], k2[4], k3[4], km[4];
#pragma unroll
        for (int r = 0; r < 4; ++r) {
            k0[r] = keyf(XS[r], A2[r], B2[r], C2[r], cx.x, cy.x, cz.x, q0);
            k1[r] = keyf(XS[r], A2[r], B2[r], C2[r], cx.y, cy.y, cz.y, q1);
            k2[r] = keyf(XS[r], A2[r], B2[r], C2[r], cx.z, cy.z, cz.z, q2);
            k3[r] = keyf(XS[r], A2[r], B2[r], C2[r], cx.w, cy.w, cz.w, q3);
            km[r] = fminf(fminf(k0[r], k1[r]), fminf(k2[r], k3[r]));
        }

        if (t == 0) {
            // warm tau0[r]: max over 16 groups (of 4 lanes) of group-mins;
            // >=16 distinct points <= tau0 -> tau0 >= true 16th of these 256.
#pragma unroll
            for (int r = 0; r < 4; ++r) {
                float g = km[r];
                g = fminf(g, __shfl_xor(g, 1));
                g = fminf(g, __shfl_xor(g, 2));
                float m = g;
                m = fmaxf(m, __shfl_xor(m, 4));
                m = fmaxf(m, __shfl_xor(m, 8));
                m = fmaxf(m, __shfl_xor(m, 16));
                m = fmaxf(m, __shfl_xor(m, 32));
                tau[r] = m;
            }
        }

#pragma unroll
        for (int r = 0; r < 4; ++r) {
            if (__ballot(km[r] <= tau[r])) {
                // per-point qualify masks -> ballot bit-planes -> prefix offsets
                unsigned long long b0 = __ballot(k0[r] <= tau[r]);
                unsigned long long b1 = __ballot(k1[r] <= tau[r]);
                unsigned long long b2 = __ballot(k2[r] <= tau[r]);
                unsigned long long b3 = __ballot(k3[r] <= tau[r]);
                int pre = prefix_lt(b0) + prefix_lt(b1) + prefix_lt(b2) + prefix_lt(b3);
                int tot = __popcll(b0) + __popcll(b1) + __popcll(b2) + __popcll(b3);
                int pos = cnt[r] + pre;
                unsigned* S = stk_sh[wid][r];
                if (k0[r] <= tau[r]) S[pos++] = (unsigned)(mofs + 0);
                if (k1[r] <= tau[r]) S[pos++] = (unsigned)(mofs + 1);
                if (k2[r] <= tau[r]) S[pos++] = (unsigned)(mofs + 2);
                if (k3[r] <= tau[r]) S[pos++] = (unsigned)(mofs + 3);
                cnt[r] += tot;                     // uniform update
                if (cnt[r] >= 64)                  // headroom: 63 + 256 <= CAP-1
                    tau[r] = rebuild_q(t16_sh[wid][r], S, cnt[r], lane,
                                       P, XS[r], A2[r], B2[r], C2[r], false);
            }
        }

        cx = nx; cy = ny; cz = nz;
    }

    // final fold of remaining stack entries
#pragma unroll
    for (int r = 0; r < 4; ++r) {
        if (cnt[r] > 0)
            rebuild_q(t16_sh[wid][r], stk_sh[wid][r], cnt[r], lane,
                      P, XS[r], A2[r], B2[r], C2[r], true);
    }
    __syncthreads();

    // tail: wave wid owns query r=wid; merge 4 chunk-top16s via 64-lane sort
    {
        unsigned long long v = t16_sh[lane >> 4][wid][lane & 15];
        v = sort64(v, lane);               // lanes 0..15 = global top-16

        if (lane < 16) {
            int idx = (int)(unsigned)v;
            float gx = P[idx];
            float gy = P[MPTS + idx];
            float gz = P[2 * MPTS + idx];
#pragma unroll
            for (int off = 8; off > 0; off >>= 1) {
                gx += __shfl_down(gx, off, 16);
                gy += __shfl_down(gy, off, 16);
                gz += __shfl_down(gz, off, 16);
            }
            if (lane == 0) {
                int n = QPB * nb + wid;
                n = (n < NQ) ? n : (NQ - 1);  // duplicate writes identical
                float* o = out + n * 15 + 3 + 3 * pc;
                o[0] = gx * 0.0625f;
                o[1] = gy * 0.0625f;
                o[2] = gz * 0.0625f;
            }
        }
    }
}

extern "C" void kernel_launch(void* const* d_in, const int* in_sizes, int n_in,
                              void* d_out, int out_size, void* d_ws, size_t ws_size,
                              hipStream_t stream) {
    const float* inp = (const float*)d_in[0];
    const float* pc0 = (const float*)d_in[1];
    const float* pc1 = (const float*)d_in[2];
    const float* pc2 = (const float*)d_in[3];
    const float* pc3 = (const float*)d_in[4];
    float* out = (float*)d_out;

    hipLaunchKernelGGL(passthrough_kernel, dim3((NQ * 3 + 255) / 256), dim3(256),
                       0, stream, inp, out);

    // 4 pcs x 641 blocks; block = 4 queries, 4 waves x 4096 points each
    hipLaunchKernelGGL(knn_kernel, dim3(4 * NBQ), dim3(256), 0, stream,
                       inp, pc0, pc1, pc2, pc3, out);
}

// Round 10
// 107.784 us; speedup vs baseline: 1.5669x; 1.5669x over previous
//
#include <hip/hip_runtime.h>
#include <stdint.h>
#include <math.h>

#define NQ    2562
#define MPTS  16384
#define QPB   8            // queries per block (4 waves x 2)
#define NBQ   321          // ceil(NQ / QPB) blocks per point cloud
#define NT    (MPTS / 256) // 64 stream iters per wave (full stream, no split)
#define CAP   320          // stack cap per (wave,query): 63 leftover + 256 worst burst

// ---------------------------------------------------------------------------
// Kernel 1: copy inputs [N,3] into output columns 0..2 of [N,15]
// ---------------------------------------------------------------------------
__global__ __launch_bounds__(256)
void passthrough_kernel(const float* __restrict__ inp, float* __restrict__ out) {
    int gid = blockIdx.x * 256 + threadIdx.x;
    if (gid < NQ * 3) {
        int n = gid / 3, c = gid - n * 3;
        out[n * 15 + c] = inp[gid];
    }
}

// key = (x^2sum + y^2sum) - 2*x.y  mirroring numpy association (left-assoc _rn,
// fma dot with pre-doubled query coords). Same formula in stream and rebuild
// -> bitwise-identical keys.
__device__ __forceinline__ float sqsum3(float y0, float y1, float y2) {
    return __fadd_rn(__fadd_rn(__fmul_rn(y0, y0), __fmul_rn(y1, y1)),
                     __fmul_rn(y2, y2));
}
__device__ __forceinline__ float keyf(float xs, float a2, float b2, float c2,
                                      float y0, float y1, float y2, float ysq) {
    float u = fmaf(c2, y2, fmaf(b2, y1, __fmul_rn(a2, y0)));
    return __fsub_rn(__fadd_rn(xs, ysq), u);
}
__device__ __forceinline__ unsigned long long packkey(float k, int m) {
    uint32_t kb = __float_as_uint(k);
    kb ^= (uint32_t)((int32_t)kb >> 31) | 0x80000000u;  // monotonic total-order map
    return ((unsigned long long)kb << 32) | (unsigned)m;
}
__device__ __forceinline__ float unmapkey(unsigned long long pk) {
    uint32_t kb = (uint32_t)(pk >> 32);
    return __uint_as_float((kb & 0x80000000u) ? (kb ^ 0x80000000u) : ~kb);
}
// popcount of mask over lanes < this lane (v_mbcnt pair)
__device__ __forceinline__ int prefix_lt(unsigned long long m) {
    return __builtin_amdgcn_mbcnt_hi((unsigned)(m >> 32),
           __builtin_amdgcn_mbcnt_lo((unsigned)m, 0u));
}

// 64-lane bitonic sort ascending; lane l ends with the l-th smallest value.
__device__ __forceinline__ unsigned long long sort64(unsigned long long v, int lane) {
#pragma unroll
    for (int k = 2; k <= 64; k <<= 1) {
#pragma unroll
        for (int j = k >> 1; j > 0; j >>= 1) {
            unsigned long long p = __shfl_xor(v, j);
            bool up = ((lane & k) == 0) == ((lane & j) == 0);
            bool sw = up ? (p < v) : (v < p);
            v = sw ? p : v;
        }
    }
    return v;
}

// Wave-collective: fold stack chunks into sorted t16 (LDS). Mid-stream
// (fin=false): process only full 64-chunks, compact remainder. Final
// (fin=true): process all. cnt is wave-uniform (register). Returns new tau.
__device__ __forceinline__ float rebuild_q(unsigned long long* t16p,
                                           unsigned* S, int& cnt, int lane,
                                           const float* __restrict__ P,
                                           float xs, float a2, float b2, float c2,
                                           bool fin) {
    int c = cnt;
    int full = c >> 6, rem = c & 63;
    int rounds = full + ((fin && rem) ? 1 : 0);
    unsigned long long v = ~0ULL;
    for (int rd = 0; rd < rounds; ++rd) {
        int i = (rd << 6) + lane;
        unsigned idx = (i < c) ? S[i] : 0u;
        float y0 = P[idx], y1 = P[MPTS + idx], y2 = P[2 * MPTS + idx];
        float key = keyf(xs, a2, b2, c2, y0, y1, y2, sqsum3(y0, y1, y2));
        unsigned long long pk = (i < c) ? packkey(key, (int)idx) : ~0ULL;
        pk = sort64(pk, lane);             // asc across lanes
        // bitonic merge: A = t16 asc (lanes 0-15), B = chunk's smallest-16 desc
        unsigned long long bsw = __shfl(pk, (31 - lane) & 63);
        v = (lane < 16) ? t16p[lane & 15] : (lane < 32) ? bsw : ~0ULL;
#pragma unroll
        for (int j = 16; j > 0; j >>= 1) {
            unsigned long long p2 = __shfl_xor(v, j);
            bool keepmin = (lane & j) == 0;
            bool less = p2 < v;
            v = (keepmin == less) ? p2 : v;
        }
        if (lane < 16) t16p[lane] = v;
    }
    if (!fin) {
        if (lane < rem) S[lane] = S[(full << 6) + lane];   // disjoint (full>=1)
        cnt = rem;
    } else {
        cnt = 0;
    }
    return unmapkey(__shfl(v, 15));
}

// ---------------------------------------------------------------------------
// Kernel 2: grid 4*NBQ x 256. Block b: pc = b/NBQ, 8 queries 8*(b%NBQ)+..;
// wave wid owns queries {8*nb + 2*wid, +1} and streams ALL 16384 points.
// No cross-wave merge, no __syncthreads. Selection: f32 tau gate + LDS index
// stack (ballot prefix offsets, SGPR counter) + batched exact folds
// (sort64 + bitonic merge) into per-wave sorted t16.
// ---------------------------------------------------------------------------
__global__ __launch_bounds__(256)
void knn_kernel(const float* __restrict__ inp,
                const float* __restrict__ pc0, const float* __restrict__ pc1,
                const float* __restrict__ pc2, const float* __restrict__ pc3,
                float* __restrict__ out) {
    const int b    = blockIdx.x;
    const int wid  = threadIdx.x >> 6;
    const int lane = threadIdx.x & 63;

    const int pc = b / NBQ;
    const int nb = b - pc * NBQ;
    const float* __restrict__ P = (pc == 0) ? pc0 : (pc == 1) ? pc1
                                : (pc == 2) ? pc2 : pc3;

    __shared__ unsigned           stk_sh[4][2][CAP];
    __shared__ unsigned long long t16_sh[4][2][16];

    if (lane < 32) t16_sh[wid][lane >> 4][lane & 15] = ~0ULL;

    // coefficients for this wave's 2 queries
    float A2[2], B2[2], C2[2], XS[2];
#pragma unroll
    for (int r = 0; r < 2; ++r) {
        int n = QPB * nb + 2 * wid + r;
        n = (n < NQ) ? n : (NQ - 1);       // tail clamp (duplicate-identical work)
        float x0 = inp[n * 3 + 0];
        float x1 = inp[n * 3 + 1];
        float x2 = inp[n * 3 + 2];
        A2[r] = 2.0f * x0;
        B2[r] = 2.0f * x1;
        C2[r] = 2.0f * x2;
        XS[r] = sqsum3(x0, x1, x2);
    }
    float tau[2];
    int   cnt[2] = {0, 0};                 // wave-uniform -> SGPR

    const float* __restrict__ Pl = P + (lane << 2);

    // push path for one 256-pt tile (k*, km precomputed); shared by warm + loop
    auto push_tile = [&](int r, int mofs, float k0, float k1, float k2, float k3) {
        unsigned long long b0 = __ballot(k0 <= tau[r]);
        unsigned long long b1 = __ballot(k1 <= tau[r]);
        unsigned long long b2 = __ballot(k2 <= tau[r]);
        unsigned long long b3 = __ballot(k3 <= tau[r]);
        int pre = prefix_lt(b0) + prefix_lt(b1) + prefix_lt(b2) + prefix_lt(b3);
        int tot = __popcll(b0) + __popcll(b1) + __popcll(b2) + __popcll(b3);
        int pos = cnt[r] + pre;
        unsigned* S = stk_sh[wid][r];
        if (k0 <= tau[r]) S[pos++] = (unsigned)(mofs + 0);
        if (k1 <= tau[r]) S[pos++] = (unsigned)(mofs + 1);
        if (k2 <= tau[r]) S[pos++] = (unsigned)(mofs + 2);
        if (k3 <= tau[r]) S[pos++] = (unsigned)(mofs + 3);
        cnt[r] += tot;
        if (cnt[r] >= 64)                  // headroom: 63 + 256 <= CAP-1
            tau[r] = rebuild_q(t16_sh[wid][r], S, cnt[r], lane,
                               P, XS[r], A2[r], B2[r], C2[r], false);
    };

    // ---- peeled t=0: warm tau + push ----
    {
        float4 ax = *(const float4*)(Pl);
        float4 ay = *(const float4*)(Pl + MPTS);
        float4 az = *(const float4*)(Pl + 2 * MPTS);
        float q0 = sqsum3(ax.x, ay.x, az.x);
        float q1 = sqsum3(ax.y, ay.y, az.y);
        float q2 = sqsum3(ax.z, ay.z, az.z);
        float q3 = sqsum3(ax.w, ay.w, az.w);
#pragma unroll
        for (int r = 0; r < 2; ++r) {
            float k0 = keyf(XS[r], A2[r], B2[r], C2[r], ax.x, ay.x, az.x, q0);
            float k1 = keyf(XS[r], A2[r], B2[r], C2[r], ax.y, ay.y, az.y, q1);
            float k2 = keyf(XS[r], A2[r], B2[r], C2[r], ax.z, ay.z, az.z, q2);
            float k3 = keyf(XS[r], A2[r], B2[r], C2[r], ax.w, ay.w, az.w, q3);
            float km = fminf(fminf(k0, k1), fminf(k2, k3));
            // warm tau0: max over 16 groups (of 4 lanes) of group-mins;
            // >=16 distinct points <= tau0 -> tau0 >= true 16th of these 256.
            float g = km;
            g = fminf(g, __shfl_xor(g, 1));
            g = fminf(g, __shfl_xor(g, 2));
            float m = g;
            m = fmaxf(m, __shfl_xor(m, 4));
            m = fmaxf(m, __shfl_xor(m, 8));
            m = fmaxf(m, __shfl_xor(m, 16));
            m = fmaxf(m, __shfl_xor(m, 32));
            tau[r] = m;
            push_tile(r, lane << 2, k0, k1, k2, k3);
        }
    }

    // prefetch t=1
    float4 cx = *(const float4*)(Pl + 256);
    float4 cy = *(const float4*)(Pl + MPTS + 256);
    float4 cz = *(const float4*)(Pl + 2 * MPTS + 256);

    for (int t = 1; t < NT; ++t) {
        const int tn = (t + 1 < NT) ? t + 1 : t;   // clamped prefetch (dup harmless)
        float4 nx = *(const float4*)(Pl + (tn << 8));
        float4 ny = *(const float4*)(Pl + MPTS + (tn << 8));
        float4 nz = *(const float4*)(Pl + 2 * MPTS + (tn << 8));

        const int mofs = (t << 8) + (lane << 2);
        float q0 = sqsum3(cx.x, cy.x, cz.x);
        float q1 = sqsum3(cx.y, cy.y, cz.y);
        float q2 = sqsum3(cx.z, cy.z, cz.z);
        float q3 = sqsum3(cx.w, cy.w, cz.w);
#pragma unroll
        for (int r = 0; r < 2; ++r) {
            float k0 = keyf(XS[r], A2[r], B2[r], C2[r], cx.x, cy.x, cz.x, q0);
            float k1 = keyf(XS[r], A2[r], B2[r], C2[r], cx.y, cy.y, cz.y, q1);
            float k2 = keyf(XS[r], A2[r], B2[r], C2[r], cx.z, cy.z, cz.z, q2);
            float k3 = keyf(XS[r], A2[r], B2[r], C2[r], cx.w, cy.w, cz.w, q3);
            float km = fminf(fminf(k0, k1), fminf(k2, k3));
            if (__ballot(km <= tau[r]))
                push_tile(r, mofs, k0, k1, k2, k3);
        }
        cx = nx; cy = ny; cz = nz;
    }

    // final fold of remaining stack entries
#pragma unroll
    for (int r = 0; r < 2; ++r) {
        if (cnt[r] > 0)
            rebuild_q(t16_sh[wid][r], stk_sh[wid][r], cnt[r], lane,
                      P, XS[r], A2[r], B2[r], C2[r], true);
    }

    // tail: 32-lane half h outputs query r=h (t16 already sorted ascending)
    {
        const int h   = lane >> 5;
        const int l32 = lane & 31;
        if (l32 < 16) {
            unsigned long long v = t16_sh[wid][h][l32];
            int idx = (int)(unsigned)v;
            float gx = P[idx];
            float gy = P[MPTS + idx];
            float gz = P[2 * MPTS + idx];
#pragma unroll
            for (int off = 8; off > 0; off >>= 1) {
                gx += __shfl_down(gx, off, 16);
                gy += __shfl_down(gy, off, 16);
                gz += __shfl_down(gz, off, 16);
            }
            if (l32 == 0) {
                int n = QPB * nb + 2 * wid + h;
                n = (n < NQ) ? n : (NQ - 1);  // duplicate writes identical
                float* o = out + n * 15 + 3 + 3 * pc;
                o[0] = gx * 0.0625f;
                o[1] = gy * 0.0625f;
                o[2] = gz * 0.0625f;
            }
        }
    }
}

extern "C" void kernel_launch(void* const* d_in, const int* in_sizes, int n_in,
                              void* d_out, int out_size, void* d_ws, size_t ws_size,
                              hipStream_t stream) {
    const float* inp = (const float*)d_in[0];
    const float* pc0 = (const float*)d_in[1];
    const float* pc1 = (const float*)d_in[2];
    const float* pc2 = (const float*)d_in[3];
    const float* pc3 = (const float*)d_in[4];
    float* out = (float*)d_out;

    hipLaunchKernelGGL(passthrough_kernel, dim3((NQ * 3 + 255) / 256), dim3(256),
                       0, stream, inp, out);

    // 4 pcs x 321 blocks; block = 8 queries, 4 waves x 2 queries, full stream
    hipLaunchKernelGGL(knn_kernel, dim3(4 * NBQ), dim3(256), 0, stream,
                       inp, pc0, pc1, pc2, pc3, out);
}